// Round 4
// baseline (118.638 us; speedup 1.0000x reference)
//
#include <hip/hip_runtime.h>

#define NN 2048
#define DD 64
#define BB 64
#define PP 16384
#define TT 262144
#define EPSF 1e-6f
#define SS ((size_t)NN * DD)  // floats between consecutive bins of v (bin-major layout)

// ---------------- ws layout (bytes) ----------------
// 0        : double acc
// 64       : float bounds[65]
// 384      : float widths[64]
// 640      : float innerPad[64]   (inner[0..62], [63]=+INF)
// 1024     : float4 table[PP*BB]  (n2_left, d0, qq, bsum)   = 16.78 MB
// 16778240 : float vT[NN*BB*DD]   (node-major transpose)    = 33.55 MB
// total ~50.4 MB (falls back to direct-v reads if ws_size too small)

template <int CTRL, int RM = 0xF, bool BC = true>
__device__ __forceinline__ float dpp_add(float x) {
    int y = __builtin_amdgcn_update_dpp(0, __float_as_int(x), CTRL, RM, 0xF, BC);
    return x + __int_as_float(y);
}

// full 64-lane sum, result on all lanes
__device__ __forceinline__ float reduce1(float a) {
    a = dpp_add<0xB1>(a);    // quad_perm xor1
    a = dpp_add<0x4E>(a);    // quad_perm xor2
    a = dpp_add<0x141>(a);   // row_half_mirror (sum of 8)
    a = dpp_add<0x140>(a);   // row_mirror (sum of 16)
    a += __int_as_float(__builtin_amdgcn_ds_swizzle(__float_as_int(a), 0x401F));  // xor16
    a += __shfl_xor(a, 32, 64);
    return a;
}

// 64-lane inclusive prefix sum (canonical 6-DPP scan)
__device__ __forceinline__ float incl_scan(float x) {
    x = dpp_add<0x111>(x);             // row_shr:1
    x = dpp_add<0x112>(x);             // row_shr:2
    x = dpp_add<0x114>(x);             // row_shr:4
    x = dpp_add<0x118>(x);             // row_shr:8
    x = dpp_add<0x142, 0xA, false>(x); // row_bcast:15 -> rows 1,3
    x = dpp_add<0x143, 0xC, false>(x); // row_bcast:31 -> rows 2,3
    return x;
}

__global__ void k_bounds(const float* __restrict__ brw, float* __restrict__ bounds,
                         float* __restrict__ widths, float* __restrict__ innerPad) {
    int lane = threadIdx.x;  // 64 threads
    float w = brw[lane];
    float m = w;
#pragma unroll
    for (int s = 32; s >= 1; s >>= 1) m = fmaxf(m, __shfl_xor(m, s, 64));
    float e = expf(w - m);
    float tot = e;
#pragma unroll
    for (int s = 32; s >= 1; s >>= 1) tot += __shfl_xor(tot, s, 64);
    float sm = e / tot;
    float c = sm;  // inclusive prefix sum
#pragma unroll
    for (int off = 1; off < 64; off <<= 1) {
        float t = __shfl_up(c, off, 64);
        if (lane >= off) c += t;
    }
    float cexcl = __shfl_up(c, 1, 64);
    if (lane == 0) cexcl = 0.f;
    if (lane == 0) bounds[0] = 0.f;
    bounds[lane + 1] = c;
    widths[lane] = c - cexcl;
    innerPad[lane] = (lane == 63) ? 3.4e38f : c;  // inner = bounds[1..63]
}

// v[b][n][d] -> vT[n][b][d]: per-node rows become one contiguous 16KB block
__global__ __launch_bounds__(256) void k_transpose(const float* __restrict__ v,
                                                   float* __restrict__ vT) {
    int wid = threadIdx.x >> 6, lane = threadIdx.x & 63;
    int n = blockIdx.x * 4 + wid;
    const float* __restrict__ src = v + (size_t)n * DD + lane;
    float* __restrict__ dst = vT + (size_t)n * BB * DD + lane;
#pragma unroll
    for (int c = 0; c < 4; c++) {
        float r[16];
#pragma unroll
        for (int b = 0; b < 16; b++) r[b] = src[(size_t)(c * 16 + b) * SS];
#pragma unroll
        for (int b = 0; b < 16; b++) dst[(c * 16 + b) * DD] = r[b];
    }
}

__global__ __launch_bounds__(256) void k_pairs(
    const float* __restrict__ x0, const float* __restrict__ vsrc,
    const float* __restrict__ beta, const int* __restrict__ pairs,
    const float* __restrict__ widths, float4* __restrict__ table,
    double* __restrict__ acc_out, size_t nodeStride, size_t rowStride) {
    __shared__ float tiles[4][2][8][65];  // [wave][d0|qq][bin-in-chunk][writer lane] (+1 pad)
    __shared__ double bacc[4];
    const int wid = threadIdx.x >> 6;
    const int lane = threadIdx.x & 63;
    const int p = blockIdx.x * 4 + wid;

    const int i = pairs[p];
    const int j = pairs[PP + p];
    const float bsum = beta[i] + beta[j];

    float dx0 = x0[i * DD + lane] - x0[j * DD + lane];
    float xt = dx0;
    float n2_0 = reduce1(dx0 * dx0);
    float rr0 = __builtin_amdgcn_sqrtf(n2_0);
    float numer0 = rr0 * __expf(bsum - rr0);

    const float* __restrict__ pi = vsrc + (size_t)i * nodeStride + lane;
    const float* __restrict__ pj = vsrc + (size_t)j * nodeStride + lane;

    float (*t_d0)[65] = tiles[wid][0];
    float (*t_qq)[65] = tiles[wid][1];

    const int br = lane >> 3;            // reader: bin within chunk
    const int e8 = (lane & 7) * 8;       // reader: column start
    const int src_pl = (lane & 7) << 5;  // bpermute byte addr: pull from lane 8*(l&7)

    float d0r = 0.f, qqr = 0.f;  // lane b ends holding bin b's reduced d0, qq

    float curA[8], curB[8];
#pragma unroll
    for (int b = 0; b < 8; b++) {
        curA[b] = pi[(size_t)b * rowStride];
        curB[b] = pj[(size_t)b * rowStride];
    }

#pragma unroll
    for (int c = 0; c < 8; c++) {
        // phase 1: per-lane partials for 8 bins -> LDS tile (2-way=free bank pattern)
#pragma unroll
        for (int b = 0; b < 8; b++) {
            float dv = curA[b] - curB[b];
            float w = widths[c * 8 + b];
            t_d0[b][lane] = xt * dv;
            t_qq[b][lane] = dv * dv;
            xt = fmaf(dv, w, xt);
        }
        // issue next chunk's 16 loads (hidden under phase 2 + TLP)
        if (c < 7) {
#pragma unroll
            for (int b = 0; b < 8; b++) {
                curA[b] = pi[(size_t)((c + 1) * 8 + b) * rowStride];
                curB[b] = pj[(size_t)((c + 1) * 8 + b) * rowStride];
            }
        }
        // phase 2: transpose-reduce; 8 lanes per bin, each sums 8 columns
        const float* r0 = &t_d0[br][e8];
        const float* r1 = &t_qq[br][e8];
        float s0 = 0.f, s1 = 0.f;
#pragma unroll
        for (int k = 0; k < 8; k++) {
            s0 += r0[k];
            s1 += r1[k];
        }
        // sum across the 8 lanes of the group: xor1, xor2, xor7 (row_half_mirror)
        s0 = dpp_add<0xB1>(s0);  s1 = dpp_add<0xB1>(s1);
        s0 = dpp_add<0x4E>(s0);  s1 = dpp_add<0x4E>(s1);
        s0 = dpp_add<0x141>(s0); s1 = dpp_add<0x141>(s1);
        // place bin (8c+k) result into lane 8c+k
        float g0 = __int_as_float(__builtin_amdgcn_ds_bpermute(src_pl, __float_as_int(s0)));
        float g1 = __int_as_float(__builtin_amdgcn_ds_bpermute(src_pl, __float_as_int(s1)));
        if ((lane >> 3) == c) { d0r = g0; qqr = g1; }
    }

    // phase 3: all 64 bins' scalar math lane-parallel
    float wl = widths[lane];
    float tt = wl * fmaf(wl, qqr, 2.f * d0r);     // n2 increment of bin `lane`
    float incl = incl_scan(tt);
    float n2L = fmaxf(n2_0 + (incl - tt), 0.f);   // left-boundary norm^2
    float n2R = fmaxf(n2_0 + incl, 0.f);          // right-boundary norm^2
    float rrR = __builtin_amdgcn_sqrtf(n2R);
    float numerR = rrR * __expf(bsum - rrR);
    int shaddr = ((lane + 63) & 63) << 2;         // pull from lane-1
    float numerL = __int_as_float(__builtin_amdgcn_ds_bpermute(shaddr, __float_as_int(numerR)));
    numerL = (lane == 0) ? numer0 : numerL;
    float pd = fmaf(wl, qqr, d0r);                // dot1 = d0 + w*qq
    float term = numerR * __builtin_amdgcn_rcpf(pd + EPSF)
               - numerL * __builtin_amdgcn_rcpf(d0r + EPSF);
    float acc = reduce1(term);

    table[(size_t)p * BB + lane] = make_float4(n2L, d0r, qqr, bsum);

    if (lane == 0) bacc[wid] = (double)acc;
    __syncthreads();
    if (threadIdx.x == 0)
        atomicAdd(acc_out, bacc[0] + bacc[1] + bacc[2] + bacc[3]);
}

__global__ __launch_bounds__(256) void k_events(
    const float* __restrict__ times, const int* __restrict__ epid,
    const float* __restrict__ bounds, const float* __restrict__ innerPad,
    const float4* __restrict__ table, double* __restrict__ acc_out) {
    __shared__ float si[64];
    __shared__ float sb[BB + 1];
    __shared__ double wacc[4];
    int tid = threadIdx.x;
    if (tid < 64) si[tid] = innerPad[tid];
    if (tid <= BB) sb[tid] = bounds[tid];
    __syncthreads();
    int t = blockIdx.x * 256 + tid;
    float tm = times[t];
    int pid = epid[t];
    int c = 0;  // searchsorted(inner, tm, 'right') via binary search over padded 64
#pragma unroll
    for (int s = 32; s >= 1; s >>= 1)
        if (si[c + s - 1] <= tm) c += s;
    float rem = tm - sb[c];
    float4 en = table[(size_t)pid * BB + c];
    float d2 = fmaxf(fmaf(rem, fmaf(rem, en.z, 2.f * en.y), en.x), 0.f);
    float val = en.w - __builtin_amdgcn_sqrtf(d2);  // bsum - dist
    val = reduce1(val);
    if ((tid & 63) == 0) wacc[tid >> 6] = (double)val;
    __syncthreads();
    if (tid == 0)
        atomicAdd(acc_out, -(wacc[0] + wacc[1] + wacc[2] + wacc[3]));
}

__global__ void k_finalize(const double* __restrict__ acc, float* __restrict__ out) {
    out[0] = (float)(*acc);
}

extern "C" void kernel_launch(void* const* d_in, const int* in_sizes, int n_in,
                              void* d_out, int out_size, void* d_ws, size_t ws_size,
                              hipStream_t stream) {
    const float* x0     = (const float*)d_in[0];
    const float* v      = (const float*)d_in[1];
    const float* beta   = (const float*)d_in[2];
    const float* brw    = (const float*)d_in[3];
    const float* etimes = (const float*)d_in[4];
    const int*   pairs  = (const int*)d_in[5];
    const int*   epid   = (const int*)d_in[6];

    char* ws = (char*)d_ws;
    double* acc     = (double*)ws;
    float* bounds   = (float*)(ws + 64);
    float* widths   = (float*)(ws + 384);
    float* innerPad = (float*)(ws + 640);
    float4* table   = (float4*)(ws + 1024);
    float* vT       = (float*)(ws + 1024 + (size_t)PP * BB * 16);

    const size_t need = 1024 + (size_t)PP * BB * 16 + (size_t)NN * BB * DD * 4;
    const bool useT = ws_size >= need;

    hipMemsetAsync(ws, 0, 64, stream);  // acc

    hipLaunchKernelGGL(k_bounds, dim3(1), dim3(64), 0, stream, brw, bounds, widths, innerPad);
    if (useT) {
        hipLaunchKernelGGL(k_transpose, dim3(NN / 4), dim3(256), 0, stream, v, vT);
        hipLaunchKernelGGL(k_pairs, dim3(PP / 4), dim3(256), 0, stream, x0, vT, beta, pairs,
                           widths, table, acc, (size_t)(BB * DD), (size_t)DD);
    } else {
        hipLaunchKernelGGL(k_pairs, dim3(PP / 4), dim3(256), 0, stream, x0, v, beta, pairs,
                           widths, table, acc, (size_t)DD, SS);
    }
    hipLaunchKernelGGL(k_events, dim3(TT / 256), dim3(256), 0, stream, etimes, epid,
                       bounds, innerPad, table, acc);
    hipLaunchKernelGGL(k_finalize, dim3(1), dim3(1), 0, stream, acc, (float*)d_out);
}

// Round 5
// 111.075 us; speedup vs baseline: 1.0681x; 1.0681x over previous
//
#include <hip/hip_runtime.h>

#define NN 2048
#define DD 64
#define BB 64
#define PP 16384
#define TT 262144
#define EPSF 1e-6f
#define SS ((size_t)NN * DD)  // floats between consecutive bins of v (bin-major)

// ---------------- ws layout (bytes) ----------------
// 0     : double acc
// 1024  : int cnt[2048]     (node-i histogram)
// 9216  : int cursor[2048]
// 17408 : int perm[PP]      (pair ids sorted by node i)
// 82944 : float bounds[65]
// 83456 : float widths[64]
// 83968 : float innerPad[64]
// 84480 : float4 table[PP*BB]  (n2_left, d0, qq, bsum) = 16.78 MB

template <int CTRL, int RM = 0xF, bool BC = true>
__device__ __forceinline__ float dpp_add(float x) {
    int y = __builtin_amdgcn_update_dpp(0, __float_as_int(x), CTRL, RM, 0xF, BC);
    return x + __int_as_float(y);
}

__device__ __forceinline__ float reduce1(float a) {
    a = dpp_add<0xB1>(a);    // quad_perm xor1
    a = dpp_add<0x4E>(a);    // quad_perm xor2
    a = dpp_add<0x141>(a);   // row_half_mirror (sum of 8)
    a = dpp_add<0x140>(a);   // row_mirror (sum of 16)
    a += __int_as_float(__builtin_amdgcn_ds_swizzle(__float_as_int(a), 0x401F));  // xor16
    a += __shfl_xor(a, 32, 64);
    return a;
}

// 64-lane inclusive prefix sum (canonical 6-DPP scan)
__device__ __forceinline__ float incl_scan(float x) {
    x = dpp_add<0x111>(x);             // row_shr:1
    x = dpp_add<0x112>(x);             // row_shr:2
    x = dpp_add<0x114>(x);             // row_shr:4
    x = dpp_add<0x118>(x);             // row_shr:8
    x = dpp_add<0x142, 0xA, false>(x); // row_bcast:15 -> rows 1,3
    x = dpp_add<0x143, 0xC, false>(x); // row_bcast:31 -> rows 2,3
    return x;
}

__device__ __forceinline__ float rlane(float v, int l) {
    return __int_as_float(__builtin_amdgcn_readlane(__float_as_int(v), l));
}

__global__ void k_bounds(const float* __restrict__ brw, float* __restrict__ bounds,
                         float* __restrict__ widths, float* __restrict__ innerPad) {
    int lane = threadIdx.x;  // 64 threads
    float w = brw[lane];
    float m = w;
#pragma unroll
    for (int s = 32; s >= 1; s >>= 1) m = fmaxf(m, __shfl_xor(m, s, 64));
    float e = expf(w - m);
    float tot = e;
#pragma unroll
    for (int s = 32; s >= 1; s >>= 1) tot += __shfl_xor(tot, s, 64);
    float sm = e / tot;
    float c = sm;  // inclusive prefix sum
#pragma unroll
    for (int off = 1; off < 64; off <<= 1) {
        float t = __shfl_up(c, off, 64);
        if (lane >= off) c += t;
    }
    float cexcl = __shfl_up(c, 1, 64);
    if (lane == 0) cexcl = 0.f;
    if (lane == 0) bounds[0] = 0.f;
    bounds[lane + 1] = c;
    widths[lane] = c - cexcl;
    innerPad[lane] = (lane == 63) ? 3.4e38f : c;  // inner = bounds[1..63]
}

__global__ void k_hist2(const int* __restrict__ pairs, int* __restrict__ cnt) {
    int t = blockIdx.x * 256 + threadIdx.x;  // t < PP; pairs[t] = node i
    atomicAdd(&cnt[pairs[t]], 1);
}

__global__ __launch_bounds__(1024) void k_scan2(const int* __restrict__ cnt,
                                                int* __restrict__ cursor) {
    __shared__ int waveTot[16];
    __shared__ int waveOff[16];
    int tid = threadIdx.x;  // 1024 threads, 2 entries each
    int a = cnt[tid * 2], b = cnt[tid * 2 + 1];
    int s = a + b;
    int lane = tid & 63, wid = tid >> 6;
    int incl = s;
#pragma unroll
    for (int off = 1; off < 64; off <<= 1) {
        int t2 = __shfl_up(incl, off, 64);
        if (lane >= off) incl += t2;
    }
    if (lane == 63) waveTot[wid] = incl;
    __syncthreads();
    if (tid == 0) {
        int r = 0;
        for (int w = 0; w < 16; w++) { waveOff[w] = r; r += waveTot[w]; }
    }
    __syncthreads();
    int run = waveOff[wid] + (incl - s);  // exclusive prefix for this thread
    cursor[tid * 2] = run;
    cursor[tid * 2 + 1] = run + a;
}

__global__ void k_scatter2(const int* __restrict__ pairs, int* __restrict__ cursor,
                           int* __restrict__ perm) {
    int t = blockIdx.x * 256 + threadIdx.x;
    int pos = atomicAdd(&cursor[pairs[t]], 1);
    perm[pos] = t;
}

__global__ __launch_bounds__(256) void k_pairs(
    const float* __restrict__ x0, const float* __restrict__ v,
    const float* __restrict__ beta, const int* __restrict__ pairs,
    const int* __restrict__ perm, const float* __restrict__ widths,
    float4* __restrict__ table, double* __restrict__ acc_out) {
    __shared__ float dvt[4][8][68];  // [wave][bin-in-chunk][dim] stride 68: b128-aligned writes
    __shared__ float d0t[4][8][65];  // partial-dot tiles, stride 65: 2-way-free scalar access
    __shared__ float qqt[4][8][65];
    __shared__ double bacc[4];
    const int wid = threadIdx.x >> 6;
    const int lane = threadIdx.x & 63;
    const int bid = blockIdx.x;
    const int vb = ((bid & 7) << 9) | (bid >> 3);  // XCD-contiguous p-ranges (4096 blocks)
    const int p = perm[vb * 4 + wid];

    const int i = pairs[p];
    const int j = pairs[PP + p];
    const float bsum = beta[i] + beta[j];

    float dx0 = x0[i * DD + lane] - x0[j * DD + lane];
    float xt = dx0;
    float n2_0 = reduce1(dx0 * dx0);
    float rr0 = __builtin_amdgcn_sqrtf(n2_0);
    float numer0 = rr0 * __expf(bsum - rr0);
    float w_all = widths[lane];

    // dwordx4 load decomposition: lane covers bin-row (li) x dim-quad (col..col+3)
    const int li = lane >> 4;
    const int col = (lane & 15) << 2;
    const float* __restrict__ Bi = v + ((size_t)li * NN + i) * DD + col;
    const float* __restrict__ Bj = v + ((size_t)li * NN + j) * DD + col;

    float (*t_dv)[68] = dvt[wid];
    float (*t_d0)[65] = d0t[wid];
    float (*t_qq)[65] = qqt[wid];

    const int br = lane >> 3;            // phase-2 reader: bin within chunk
    const int e8 = (lane & 7) * 8;       // phase-2 reader: column start
    const int src_pl = (lane & 7) << 5;  // bpermute: pull from lane 8*(l&7)

    float d0r = 0.f, qqr = 0.f;  // lane b ends holding bin b's reduced d0, qq

    float4 a0 = *(const float4*)(Bi);
    float4 a1 = *(const float4*)(Bi + 4 * SS);
    float4 b0 = *(const float4*)(Bj);
    float4 b1 = *(const float4*)(Bj + 4 * SS);

#pragma unroll
    for (int c = 0; c < 8; c++) {
        float4 na0, na1, nb0, nb1;
        if (c < 7) {  // 1-chunk-ahead prefetch (4 x dwordx4 = same bytes as 16 dwords)
            const float* Ni = Bi + (size_t)(c + 1) * 8 * SS;
            const float* Nj = Bj + (size_t)(c + 1) * 8 * SS;
            na0 = *(const float4*)(Ni);
            na1 = *(const float4*)(Ni + 4 * SS);
            nb0 = *(const float4*)(Nj);
            nb1 = *(const float4*)(Nj + 4 * SS);
        } else {
            na0 = a0; na1 = a1; nb0 = b0; nb1 = b1;
        }
        // dv -> LDS (bin-major rows), b128 stores
        float4 dv0, dv1;
        dv0.x = a0.x - b0.x; dv0.y = a0.y - b0.y; dv0.z = a0.z - b0.z; dv0.w = a0.w - b0.w;
        dv1.x = a1.x - b1.x; dv1.y = a1.y - b1.y; dv1.z = a1.z - b1.z; dv1.w = a1.w - b1.w;
        *(float4*)&t_dv[li][col] = dv0;       // rows 0..3
        *(float4*)&t_dv[4 + li][col] = dv1;   // rows 4..7

        // phase 1: dim-major sweep; lane owns dim `lane`
#pragma unroll
        for (int b = 0; b < 8; b++) {
            float dv = t_dv[b][lane];
            t_d0[b][lane] = xt * dv;
            t_qq[b][lane] = dv * dv;
            xt = fmaf(dv, rlane(w_all, c * 8 + b), xt);
        }
        // phase 2: transpose-reduce; 8 lanes per bin, each sums 8 columns
        const float* r0 = &t_d0[br][e8];
        const float* r1 = &t_qq[br][e8];
        float s0 = 0.f, s1 = 0.f;
#pragma unroll
        for (int k = 0; k < 8; k++) {
            s0 += r0[k];
            s1 += r1[k];
        }
        s0 = dpp_add<0xB1>(s0);  s1 = dpp_add<0xB1>(s1);
        s0 = dpp_add<0x4E>(s0);  s1 = dpp_add<0x4E>(s1);
        s0 = dpp_add<0x141>(s0); s1 = dpp_add<0x141>(s1);
        float g0 = __int_as_float(__builtin_amdgcn_ds_bpermute(src_pl, __float_as_int(s0)));
        float g1 = __int_as_float(__builtin_amdgcn_ds_bpermute(src_pl, __float_as_int(s1)));
        if ((lane >> 3) == c) { d0r = g0; qqr = g1; }

        a0 = na0; a1 = na1; b0 = nb0; b1 = nb1;
    }

    // phase 3: all 64 bins' scalar math lane-parallel
    float wl = w_all;
    float tt = wl * fmaf(wl, qqr, 2.f * d0r);     // n2 increment of bin `lane`
    float incl = incl_scan(tt);
    float n2L = fmaxf(n2_0 + (incl - tt), 0.f);   // left-boundary norm^2
    float n2R = fmaxf(n2_0 + incl, 0.f);          // right-boundary norm^2
    float rrR = __builtin_amdgcn_sqrtf(n2R);
    float numerR = rrR * __expf(bsum - rrR);
    int shaddr = ((lane + 63) & 63) << 2;         // pull from lane-1
    float numerL = __int_as_float(__builtin_amdgcn_ds_bpermute(shaddr, __float_as_int(numerR)));
    numerL = (lane == 0) ? numer0 : numerL;
    float pd = fmaf(wl, qqr, d0r);                // dot1 = d0 + w*qq
    float term = numerR * __builtin_amdgcn_rcpf(pd + EPSF)
               - numerL * __builtin_amdgcn_rcpf(d0r + EPSF);
    float acc = reduce1(term);

    table[(size_t)p * BB + lane] = make_float4(n2L, d0r, qqr, bsum);

    if (lane == 0) bacc[wid] = (double)acc;
    __syncthreads();
    if (threadIdx.x == 0)
        atomicAdd(acc_out, bacc[0] + bacc[1] + bacc[2] + bacc[3]);
}

__global__ __launch_bounds__(256) void k_events(
    const float* __restrict__ times, const int* __restrict__ epid,
    const float* __restrict__ bounds, const float* __restrict__ innerPad,
    const float4* __restrict__ table, double* __restrict__ acc_out) {
    __shared__ float si[64];
    __shared__ float sb[BB + 1];
    __shared__ double wacc[4];
    int tid = threadIdx.x;
    if (tid < 64) si[tid] = innerPad[tid];
    if (tid <= BB) sb[tid] = bounds[tid];
    __syncthreads();
    int t = blockIdx.x * 256 + tid;
    float tm = times[t];
    int pid = epid[t];
    int c = 0;  // searchsorted(inner, tm, 'right') via binary search over padded 64
#pragma unroll
    for (int s = 32; s >= 1; s >>= 1)
        if (si[c + s - 1] <= tm) c += s;
    float rem = tm - sb[c];
    float4 en = table[(size_t)pid * BB + c];
    float d2 = fmaxf(fmaf(rem, fmaf(rem, en.z, 2.f * en.y), en.x), 0.f);
    float val = en.w - __builtin_amdgcn_sqrtf(d2);  // bsum - dist
    val = reduce1(val);
    if ((tid & 63) == 0) wacc[tid >> 6] = (double)val;
    __syncthreads();
    if (tid == 0)
        atomicAdd(acc_out, -(wacc[0] + wacc[1] + wacc[2] + wacc[3]));
}

__global__ void k_finalize(const double* __restrict__ acc, float* __restrict__ out) {
    out[0] = (float)(*acc);
}

extern "C" void kernel_launch(void* const* d_in, const int* in_sizes, int n_in,
                              void* d_out, int out_size, void* d_ws, size_t ws_size,
                              hipStream_t stream) {
    const float* x0     = (const float*)d_in[0];
    const float* v      = (const float*)d_in[1];
    const float* beta   = (const float*)d_in[2];
    const float* brw    = (const float*)d_in[3];
    const float* etimes = (const float*)d_in[4];
    const int*   pairs  = (const int*)d_in[5];
    const int*   epid   = (const int*)d_in[6];

    char* ws = (char*)d_ws;
    double* acc     = (double*)ws;
    int* cnt        = (int*)(ws + 1024);
    int* cursor     = (int*)(ws + 9216);
    int* perm       = (int*)(ws + 17408);
    float* bounds   = (float*)(ws + 82944);
    float* widths   = (float*)(ws + 83456);
    float* innerPad = (float*)(ws + 83968);
    float4* table   = (float4*)(ws + 84480);

    hipMemsetAsync(ws, 0, 9216, stream);  // acc + cnt

    hipLaunchKernelGGL(k_bounds, dim3(1), dim3(64), 0, stream, brw, bounds, widths, innerPad);
    hipLaunchKernelGGL(k_hist2, dim3(PP / 256), dim3(256), 0, stream, pairs, cnt);
    hipLaunchKernelGGL(k_scan2, dim3(1), dim3(1024), 0, stream, cnt, cursor);
    hipLaunchKernelGGL(k_scatter2, dim3(PP / 256), dim3(256), 0, stream, pairs, cursor, perm);
    hipLaunchKernelGGL(k_pairs, dim3(PP / 4), dim3(256), 0, stream, x0, v, beta, pairs,
                       perm, widths, table, acc);
    hipLaunchKernelGGL(k_events, dim3(TT / 256), dim3(256), 0, stream, etimes, epid,
                       bounds, innerPad, table, acc);
    hipLaunchKernelGGL(k_finalize, dim3(1), dim3(1), 0, stream, acc, (float*)d_out);
}

// Round 6
// 105.356 us; speedup vs baseline: 1.1261x; 1.0543x over previous
//
#include <hip/hip_runtime.h>

#define NN 2048
#define DD 64
#define BB 64
#define PP 16384
#define TT 262144
#define EPSF 1e-6f
#define SS ((size_t)NN * DD)  // floats between consecutive bins of v (bin-major)

// ---------------- ws layout (bytes) ----------------
// 0     : double acc
// 1024  : int cnt[2048]     (node-i histogram)
// 9216  : int cursor[2048]
// 17408 : int perm[PP]      (pair ids sorted by node i)
// 82944 : float bounds[65]
// 83456 : float widths[64]
// 83968 : float innerPad[64]
// 84480 : float4 table[PP*BB]  (n2_left, d0, qq, bsum) = 16.78 MB

typedef unsigned uv2 __attribute__((ext_vector_type(2)));

template <int CTRL, int RM = 0xF, bool BC = true>
__device__ __forceinline__ float dpp_add(float x) {
    int y = __builtin_amdgcn_update_dpp(0, __float_as_int(x), CTRL, RM, 0xF, BC);
    return x + __int_as_float(y);
}

// xor16 / xor32 adds on the VALU pipe (permlane swaps), LDS fallback if absent
__device__ __forceinline__ float xor16_add(float x) {
#if __has_builtin(__builtin_amdgcn_permlane16_swap)
    uv2 r = __builtin_amdgcn_permlane16_swap(__float_as_uint(x), __float_as_uint(x),
                                             false, false);
    return __uint_as_float(r.x) + __uint_as_float(r.y);
#else
    return x + __int_as_float(__builtin_amdgcn_ds_swizzle(__float_as_int(x), 0x401F));
#endif
}
__device__ __forceinline__ float xor32_add(float x) {
#if __has_builtin(__builtin_amdgcn_permlane32_swap)
    uv2 r = __builtin_amdgcn_permlane32_swap(__float_as_uint(x), __float_as_uint(x),
                                             false, false);
    return __uint_as_float(r.x) + __uint_as_float(r.y);
#else
    return x + __shfl_xor(x, 32, 64);
#endif
}

// full 64-lane sum, result on all lanes — zero LDS ops (permlane path)
__device__ __forceinline__ float reduce1(float a) {
    a = dpp_add<0xB1>(a);    // quad_perm xor1
    a = dpp_add<0x4E>(a);    // quad_perm xor2
    a = dpp_add<0x141>(a);   // row_half_mirror (sum of 8)
    a = dpp_add<0x140>(a);   // row_mirror (sum of 16)
    a = xor16_add(a);
    a = xor32_add(a);
    return a;
}

__device__ __forceinline__ void reduce2(float& a, float& b) {
    a = dpp_add<0xB1>(a);  b = dpp_add<0xB1>(b);
    a = dpp_add<0x4E>(a);  b = dpp_add<0x4E>(b);
    a = dpp_add<0x141>(a); b = dpp_add<0x141>(b);
    a = dpp_add<0x140>(a); b = dpp_add<0x140>(b);
    a = xor16_add(a);      b = xor16_add(b);
    a = xor32_add(a);      b = xor32_add(b);
}

// 64-lane inclusive prefix sum (canonical 6-DPP scan)
__device__ __forceinline__ float incl_scan(float x) {
    x = dpp_add<0x111>(x);             // row_shr:1
    x = dpp_add<0x112>(x);             // row_shr:2
    x = dpp_add<0x114>(x);             // row_shr:4
    x = dpp_add<0x118>(x);             // row_shr:8
    x = dpp_add<0x142, 0xA, false>(x); // row_bcast:15 -> rows 1,3
    x = dpp_add<0x143, 0xC, false>(x); // row_bcast:31 -> rows 2,3
    return x;
}

__device__ __forceinline__ float rlane(float v, int l) {
    return __int_as_float(__builtin_amdgcn_readlane(__float_as_int(v), l));
}

__global__ void k_bounds(const float* __restrict__ brw, float* __restrict__ bounds,
                         float* __restrict__ widths, float* __restrict__ innerPad) {
    int lane = threadIdx.x;  // 64 threads
    float w = brw[lane];
    float m = w;
#pragma unroll
    for (int s = 32; s >= 1; s >>= 1) m = fmaxf(m, __shfl_xor(m, s, 64));
    float e = expf(w - m);
    float tot = e;
#pragma unroll
    for (int s = 32; s >= 1; s >>= 1) tot += __shfl_xor(tot, s, 64);
    float sm = e / tot;
    float c = sm;  // inclusive prefix sum
#pragma unroll
    for (int off = 1; off < 64; off <<= 1) {
        float t = __shfl_up(c, off, 64);
        if (lane >= off) c += t;
    }
    float cexcl = __shfl_up(c, 1, 64);
    if (lane == 0) cexcl = 0.f;
    if (lane == 0) bounds[0] = 0.f;
    bounds[lane + 1] = c;
    widths[lane] = c - cexcl;
    innerPad[lane] = (lane == 63) ? 3.4e38f : c;  // inner = bounds[1..63]
}

__global__ void k_hist2(const int* __restrict__ pairs, int* __restrict__ cnt) {
    int t = blockIdx.x * 256 + threadIdx.x;  // t < PP; pairs[t] = node i
    atomicAdd(&cnt[pairs[t]], 1);
}

__global__ __launch_bounds__(1024) void k_scan2(const int* __restrict__ cnt,
                                                int* __restrict__ cursor) {
    __shared__ int waveTot[16];
    __shared__ int waveOff[16];
    int tid = threadIdx.x;  // 1024 threads, 2 entries each
    int a = cnt[tid * 2], b = cnt[tid * 2 + 1];
    int s = a + b;
    int lane = tid & 63, wid = tid >> 6;
    int incl = s;
#pragma unroll
    for (int off = 1; off < 64; off <<= 1) {
        int t2 = __shfl_up(incl, off, 64);
        if (lane >= off) incl += t2;
    }
    if (lane == 63) waveTot[wid] = incl;
    __syncthreads();
    if (tid == 0) {
        int r = 0;
        for (int w = 0; w < 16; w++) { waveOff[w] = r; r += waveTot[w]; }
    }
    __syncthreads();
    int run = waveOff[wid] + (incl - s);  // exclusive prefix for this thread
    cursor[tid * 2] = run;
    cursor[tid * 2 + 1] = run + a;
}

__global__ void k_scatter2(const int* __restrict__ pairs, int* __restrict__ cursor,
                           int* __restrict__ perm) {
    int t = blockIdx.x * 256 + threadIdx.x;
    int pos = atomicAdd(&cursor[pairs[t]], 1);
    perm[pos] = t;
}

__global__ __launch_bounds__(256, 6) void k_pairs(
    const float* __restrict__ x0, const float* __restrict__ v,
    const float* __restrict__ beta, const int* __restrict__ pairs,
    const int* __restrict__ perm, const float* __restrict__ widths,
    float4* __restrict__ table, double* __restrict__ acc_out) {
    __shared__ double bacc[4];
    const int wid = threadIdx.x >> 6;
    const int lane = threadIdx.x & 63;
    const int bid = blockIdx.x;
    const int vb = ((bid & 7) << 9) | (bid >> 3);  // XCD-contiguous p-ranges (4096 blocks)
    const int p = perm[vb * 4 + wid];

    const int i = pairs[p];
    const int j = pairs[PP + p];
    const float bsum = beta[i] + beta[j];

    float dx0 = x0[i * DD + lane] - x0[j * DD + lane];
    float xt = dx0;
    float n2_0 = reduce1(dx0 * dx0);
    float rr0 = __builtin_amdgcn_sqrtf(n2_0);
    float numer0 = rr0 * __expf(bsum - rr0);
    float w_all = widths[lane];

    const float* __restrict__ pi = v + (size_t)i * DD + lane;
    const float* __restrict__ pj = v + (size_t)j * DD + lane;

    float d0r = 0.f, qqr = 0.f;  // lane b ends holding bin b's reduced d0, qq
    float curA[8], curB[8], nxtA[8], nxtB[8];
#pragma unroll
    for (int b = 0; b < 8; b++) {
        curA[b] = pi[(size_t)b * SS];
        curB[b] = pj[(size_t)b * SS];
    }

#pragma unroll
    for (int c = 0; c < 8; c++) {
        if (c < 7) {  // 1-chunk-ahead prefetch (16 coalesced dword loads)
#pragma unroll
            for (int b = 0; b < 8; b++) {
                nxtA[b] = pi[(size_t)((c + 1) * 8 + b) * SS];
                nxtB[b] = pj[(size_t)((c + 1) * 8 + b) * SS];
            }
        }
#pragma unroll
        for (int b = 0; b < 8; b++) {
            float dv = curA[b] - curB[b];
            float d0p = xt * dv;
            float qqp = dv * dv;
            reduce2(d0p, qqp);              // pure-VALU 64-lane sums
            const int bin = c * 8 + b;
            if (lane == bin) { d0r = d0p; qqr = qqp; }
            xt = fmaf(dv, rlane(w_all, bin), xt);
        }
#pragma unroll
        for (int b = 0; b < 8; b++) { curA[b] = nxtA[b]; curB[b] = nxtB[b]; }
    }

    // phase 3: all 64 bins' scalar math lane-parallel (lane = bin)
    float wl = w_all;
    float tt = wl * fmaf(wl, qqr, 2.f * d0r);     // n2 increment of bin `lane`
    float incl = incl_scan(tt);
    float n2L = fmaxf(n2_0 + (incl - tt), 0.f);   // left-boundary norm^2
    float n2R = fmaxf(n2_0 + incl, 0.f);          // right-boundary norm^2
    float rrR = __builtin_amdgcn_sqrtf(n2R);
    float numerR = rrR * __expf(bsum - rrR);
    int shaddr = ((lane + 63) & 63) << 2;         // pull from lane-1
    float numerL = __int_as_float(__builtin_amdgcn_ds_bpermute(shaddr, __float_as_int(numerR)));
    numerL = (lane == 0) ? numer0 : numerL;
    float pd = fmaf(wl, qqr, d0r);                // dot1 = d0 + w*qq
    float term = numerR * __builtin_amdgcn_rcpf(pd + EPSF)
               - numerL * __builtin_amdgcn_rcpf(d0r + EPSF);
    float acc = reduce1(term);

    table[(size_t)p * BB + lane] = make_float4(n2L, d0r, qqr, bsum);

    if (lane == 0) bacc[wid] = (double)acc;
    __syncthreads();
    if (threadIdx.x == 0)
        atomicAdd(acc_out, bacc[0] + bacc[1] + bacc[2] + bacc[3]);
}

__global__ __launch_bounds__(256) void k_events(
    const float* __restrict__ times, const int* __restrict__ epid,
    const float* __restrict__ bounds, const float* __restrict__ innerPad,
    const float4* __restrict__ table, double* __restrict__ acc_out) {
    __shared__ float si[64];
    __shared__ float sb[BB + 1];
    __shared__ double wacc[4];
    int tid = threadIdx.x;
    if (tid < 64) si[tid] = innerPad[tid];
    if (tid <= BB) sb[tid] = bounds[tid];
    __syncthreads();
    int g = (blockIdx.x * 256 + tid) * 4;          // 4 events per thread
    float4 tm4 = *(const float4*)(times + g);
    int4 pd4 = *(const int4*)(epid + g);
    float tms[4] = {tm4.x, tm4.y, tm4.z, tm4.w};
    int pids[4] = {pd4.x, pd4.y, pd4.z, pd4.w};
    int cc[4];
    float rem[4];
#pragma unroll
    for (int k = 0; k < 4; k++) {
        int c = 0;  // searchsorted(inner, tm, 'right') via binary search over padded 64
        float tm = tms[k];
#pragma unroll
        for (int s = 32; s >= 1; s >>= 1)
            if (si[c + s - 1] <= tm) c += s;
        cc[k] = c;
        rem[k] = tm - sb[c];
    }
    // 4 independent gathers in flight together
    float4 e0 = table[(size_t)pids[0] * BB + cc[0]];
    float4 e1 = table[(size_t)pids[1] * BB + cc[1]];
    float4 e2 = table[(size_t)pids[2] * BB + cc[2]];
    float4 e3 = table[(size_t)pids[3] * BB + cc[3]];
    float eacc = 0.f;
    {
        float d2 = fmaxf(fmaf(rem[0], fmaf(rem[0], e0.z, 2.f * e0.y), e0.x), 0.f);
        eacc += e0.w - __builtin_amdgcn_sqrtf(d2);
        d2 = fmaxf(fmaf(rem[1], fmaf(rem[1], e1.z, 2.f * e1.y), e1.x), 0.f);
        eacc += e1.w - __builtin_amdgcn_sqrtf(d2);
        d2 = fmaxf(fmaf(rem[2], fmaf(rem[2], e2.z, 2.f * e2.y), e2.x), 0.f);
        eacc += e2.w - __builtin_amdgcn_sqrtf(d2);
        d2 = fmaxf(fmaf(rem[3], fmaf(rem[3], e3.z, 2.f * e3.y), e3.x), 0.f);
        eacc += e3.w - __builtin_amdgcn_sqrtf(d2);
    }
    float val = reduce1(eacc);
    if ((tid & 63) == 0) wacc[tid >> 6] = (double)val;
    __syncthreads();
    if (tid == 0)
        atomicAdd(acc_out, -(wacc[0] + wacc[1] + wacc[2] + wacc[3]));
}

__global__ void k_finalize(const double* __restrict__ acc, float* __restrict__ out) {
    out[0] = (float)(*acc);
}

extern "C" void kernel_launch(void* const* d_in, const int* in_sizes, int n_in,
                              void* d_out, int out_size, void* d_ws, size_t ws_size,
                              hipStream_t stream) {
    const float* x0     = (const float*)d_in[0];
    const float* v      = (const float*)d_in[1];
    const float* beta   = (const float*)d_in[2];
    const float* brw    = (const float*)d_in[3];
    const float* etimes = (const float*)d_in[4];
    const int*   pairs  = (const int*)d_in[5];
    const int*   epid   = (const int*)d_in[6];

    char* ws = (char*)d_ws;
    double* acc     = (double*)ws;
    int* cnt        = (int*)(ws + 1024);
    int* cursor     = (int*)(ws + 9216);
    int* perm       = (int*)(ws + 17408);
    float* bounds   = (float*)(ws + 82944);
    float* widths   = (float*)(ws + 83456);
    float* innerPad = (float*)(ws + 83968);
    float4* table   = (float4*)(ws + 84480);

    hipMemsetAsync(ws, 0, 9216, stream);  // acc + cnt

    hipLaunchKernelGGL(k_bounds, dim3(1), dim3(64), 0, stream, brw, bounds, widths, innerPad);
    hipLaunchKernelGGL(k_hist2, dim3(PP / 256), dim3(256), 0, stream, pairs, cnt);
    hipLaunchKernelGGL(k_scan2, dim3(1), dim3(1024), 0, stream, cnt, cursor);
    hipLaunchKernelGGL(k_scatter2, dim3(PP / 256), dim3(256), 0, stream, pairs, cursor, perm);
    hipLaunchKernelGGL(k_pairs, dim3(PP / 4), dim3(256), 0, stream, x0, v, beta, pairs,
                       perm, widths, table, acc);
    hipLaunchKernelGGL(k_events, dim3(TT / 1024), dim3(256), 0, stream, etimes, epid,
                       bounds, innerPad, table, acc);
    hipLaunchKernelGGL(k_finalize, dim3(1), dim3(1), 0, stream, acc, (float*)d_out);
}

// Round 8
// 99.474 us; speedup vs baseline: 1.1927x; 1.0591x over previous
//
#include <hip/hip_runtime.h>

#define NN 2048
#define DD 64
#define BB 64
#define PP 16384
#define TT 262144
#define EPSF 1e-6f
#define SS ((size_t)NN * DD)  // floats between consecutive bins of v (bin-major)

// ---------------- ws layout (bytes) ----------------
// 0     : double acc
// 1024  : int cnt[2048]     (node-i histogram)
// 9216  : int cursor[2048]
// 17408 : int perm[PP]      (pair ids sorted by node i)
// 82944 : float bounds[65]
// 83456 : float widths[64]
// 83968 : float innerPad[64]
// 84480 : float4 table[PP*BB]  (n2_left, d0, qq, bsum) = 16.78 MB

typedef unsigned uv2 __attribute__((ext_vector_type(2)));

template <int CTRL, int RM = 0xF, bool BC = true>
__device__ __forceinline__ float dpp_add(float x) {
    int y = __builtin_amdgcn_update_dpp(0, __float_as_int(x), CTRL, RM, 0xF, BC);
    return x + __int_as_float(y);
}

template <int PAT>
__device__ __forceinline__ float swz_add(float x) {
    return x + __int_as_float(__builtin_amdgcn_ds_swizzle(__float_as_int(x), PAT));
}

// xor16 / xor32 adds on the VALU pipe (permlane swaps), LDS fallback if absent
__device__ __forceinline__ float xor16_add(float x) {
#if __has_builtin(__builtin_amdgcn_permlane16_swap)
    uv2 r = __builtin_amdgcn_permlane16_swap(__float_as_uint(x), __float_as_uint(x),
                                             false, false);
    return __uint_as_float(r.x) + __uint_as_float(r.y);
#else
    return swz_add<0x401F>(x);
#endif
}
__device__ __forceinline__ float xor32_add(float x) {
#if __has_builtin(__builtin_amdgcn_permlane32_swap)
    uv2 r = __builtin_amdgcn_permlane32_swap(__float_as_uint(x), __float_as_uint(x),
                                             false, false);
    return __uint_as_float(r.x) + __uint_as_float(r.y);
#else
    return x + __shfl_xor(x, 32, 64);
#endif
}

// full 64-lane sum, result on all lanes
__device__ __forceinline__ float reduce1(float a) {
    a = dpp_add<0xB1>(a);     // quad_perm xor1
    a = dpp_add<0x4E>(a);     // quad_perm xor2
    a = dpp_add<0x141>(a);    // row_half_mirror (completes sum of 8)
    a = swz_add<0x201F>(a);   // xor8
    a = xor16_add(a);
    a = xor32_add(a);
    return a;
}

// 64-lane inclusive prefix sum (canonical 6-DPP scan)
__device__ __forceinline__ float incl_scan(float x) {
    x = dpp_add<0x111>(x);             // row_shr:1
    x = dpp_add<0x112>(x);             // row_shr:2
    x = dpp_add<0x114>(x);             // row_shr:4
    x = dpp_add<0x118>(x);             // row_shr:8
    x = dpp_add<0x142, 0xA, false>(x); // row_bcast:15 -> rows 1,3
    x = dpp_add<0x143, 0xC, false>(x); // row_bcast:31 -> rows 2,3
    return x;
}

__device__ __forceinline__ float rlane(float v, int l) {
    return __int_as_float(__builtin_amdgcn_readlane(__float_as_int(v), l));
}

__global__ void k_bounds(const float* __restrict__ brw, float* __restrict__ bounds,
                         float* __restrict__ widths, float* __restrict__ innerPad) {
    int lane = threadIdx.x;  // 64 threads
    float w = brw[lane];
    float m = w;
#pragma unroll
    for (int s = 32; s >= 1; s >>= 1) m = fmaxf(m, __shfl_xor(m, s, 64));
    float e = expf(w - m);
    float tot = e;
#pragma unroll
    for (int s = 32; s >= 1; s >>= 1) tot += __shfl_xor(tot, s, 64);
    float sm = e / tot;
    float c = sm;  // inclusive prefix sum
#pragma unroll
    for (int off = 1; off < 64; off <<= 1) {
        float t = __shfl_up(c, off, 64);
        if (lane >= off) c += t;
    }
    float cexcl = __shfl_up(c, 1, 64);
    if (lane == 0) cexcl = 0.f;
    if (lane == 0) bounds[0] = 0.f;
    bounds[lane + 1] = c;
    widths[lane] = c - cexcl;
    innerPad[lane] = (lane == 63) ? 3.4e38f : c;  // inner = bounds[1..63]
}

__global__ void k_hist2(const int* __restrict__ pairs, int* __restrict__ cnt) {
    int t = blockIdx.x * 256 + threadIdx.x;  // t < PP; pairs[t] = node i
    atomicAdd(&cnt[pairs[t]], 1);
}

__global__ __launch_bounds__(1024) void k_scan2(const int* __restrict__ cnt,
                                                int* __restrict__ cursor) {
    __shared__ int waveTot[16];
    __shared__ int waveOff[16];
    int tid = threadIdx.x;  // 1024 threads, 2 entries each
    int a = cnt[tid * 2], b = cnt[tid * 2 + 1];
    int s = a + b;
    int lane = tid & 63, wid = tid >> 6;
    int incl = s;
#pragma unroll
    for (int off = 1; off < 64; off <<= 1) {
        int t2 = __shfl_up(incl, off, 64);
        if (lane >= off) incl += t2;
    }
    if (lane == 63) waveTot[wid] = incl;
    __syncthreads();
    if (tid == 0) {
        int r = 0;
        for (int w = 0; w < 16; w++) { waveOff[w] = r; r += waveTot[w]; }
    }
    __syncthreads();
    int run = waveOff[wid] + (incl - s);  // exclusive prefix for this thread
    cursor[tid * 2] = run;
    cursor[tid * 2 + 1] = run + a;
}

__global__ void k_scatter2(const int* __restrict__ pairs, int* __restrict__ cursor,
                           int* __restrict__ perm) {
    int t = blockIdx.x * 256 + threadIdx.x;
    int pos = atomicAdd(&cursor[pairs[t]], 1);
    perm[pos] = t;
}

__global__ __launch_bounds__(256) void k_pairs(
    const float* __restrict__ x0, const float* __restrict__ v,
    const float* __restrict__ beta, const int* __restrict__ pairs,
    const int* __restrict__ perm, const float* __restrict__ widths,
    float4* __restrict__ table, double* __restrict__ acc_out) {
    __shared__ double bacc[4];
    const int wid = threadIdx.x >> 6;
    const int lane = threadIdx.x & 63;
    const int bid = blockIdx.x;
    const int vb = ((bid & 7) << 9) | (bid >> 3);  // XCD-contiguous p-ranges (4096 blocks)
    const int p = perm[vb * 4 + wid];

    const int i = pairs[p];
    const int j = pairs[PP + p];
    const float bsum = beta[i] + beta[j];

    float dx0 = x0[i * DD + lane] - x0[j * DD + lane];
    float xt = dx0;
    float n2_0 = reduce1(dx0 * dx0);
    float rr0 = __builtin_amdgcn_sqrtf(n2_0);
    float numer0 = rr0 * __expf(bsum - rr0);
    float w_all = widths[lane];

    const float* __restrict__ pi = v + (size_t)i * DD + lane;
    const float* __restrict__ pj = v + (size_t)j * DD + lane;

    const int cls = lane & 7;   // class-select id
    const int grp = lane >> 3;  // chunk-gate id

    float d0r = 0.f, qqr = 0.f;  // lane b ends holding bin b's reduced d0, qq
    float curA[8], curB[8], nxtA[8], nxtB[8];
#pragma unroll
    for (int b = 0; b < 8; b++) {
        curA[b] = pi[(size_t)b * SS];
        curB[b] = pj[(size_t)b * SS];
    }

#pragma unroll
    for (int c = 0; c < 8; c++) {
        if (c < 7) {  // 1-chunk-ahead prefetch (16 coalesced dword loads)
#pragma unroll
            for (int b = 0; b < 8; b++) {
                nxtA[b] = pi[(size_t)((c + 1) * 8 + b) * SS];
                nxtB[b] = pj[(size_t)((c + 1) * 8 + b) * SS];
            }
        }
        float zd = 0.f, zq = 0.f;  // lane l: class-(l>>3) partial of bin (8c + (l&7))
#pragma unroll
        for (int b = 0; b < 8; b++) {
            float dv = curA[b] - curB[b];
            float d0p = xt * dv;
            float qqp = dv * dv;
            // 3 DPP levels: every lane of each 8-lane group holds that group's sum
            d0p = dpp_add<0xB1>(d0p);  qqp = dpp_add<0xB1>(qqp);   // xor1
            d0p = dpp_add<0x4E>(d0p);  qqp = dpp_add<0x4E>(qqp);   // xor2
            d0p = dpp_add<0x141>(d0p); qqp = dpp_add<0x141>(qqp);  // half-mirror
            if (cls == b) { zd = d0p; zq = qqp; }  // stash bin b's partials
            xt = fmaf(dv, rlane(w_all, c * 8 + b), xt);
        }
        // cross-class reduce for all 8 bins at once: sum lanes {b, b+8, ..., b+56}
        zd = swz_add<0x201F>(zd);  zq = swz_add<0x201F>(zq);  // xor8
        zd = xor16_add(zd);        zq = xor16_add(zq);
        zd = xor32_add(zd);        zq = xor32_add(zq);
        // lane l now holds the full sum of bin 8c+(l&7); keep where lane==bin
        if (grp == c) { d0r = zd; qqr = zq; }
#pragma unroll
        for (int b = 0; b < 8; b++) { curA[b] = nxtA[b]; curB[b] = nxtB[b]; }
    }

    // phase 3: all 64 bins' scalar math lane-parallel (lane = bin)
    float wl = w_all;
    float tt = wl * fmaf(wl, qqr, 2.f * d0r);     // n2 increment of bin `lane`
    float incl = incl_scan(tt);
    float n2L = fmaxf(n2_0 + (incl - tt), 0.f);   // left-boundary norm^2
    float n2R = fmaxf(n2_0 + incl, 0.f);          // right-boundary norm^2
    float rrR = __builtin_amdgcn_sqrtf(n2R);
    float numerR = rrR * __expf(bsum - rrR);
    int shaddr = ((lane + 63) & 63) << 2;         // pull from lane-1
    float numerL = __int_as_float(__builtin_amdgcn_ds_bpermute(shaddr, __float_as_int(numerR)));
    numerL = (lane == 0) ? numer0 : numerL;
    float pd = fmaf(wl, qqr, d0r);                // dot1 = d0 + w*qq
    float term = numerR * __builtin_amdgcn_rcpf(pd + EPSF)
               - numerL * __builtin_amdgcn_rcpf(d0r + EPSF);
    float acc = reduce1(term);

    table[(size_t)p * BB + lane] = make_float4(n2L, d0r, qqr, bsum);

    if (lane == 0) bacc[wid] = (double)acc;
    __syncthreads();
    if (threadIdx.x == 0)
        atomicAdd(acc_out, bacc[0] + bacc[1] + bacc[2] + bacc[3]);
}

__global__ __launch_bounds__(256) void k_events(
    const float* __restrict__ times, const int* __restrict__ epid,
    const float* __restrict__ bounds, const float* __restrict__ innerPad,
    const float4* __restrict__ table, double* __restrict__ acc_out) {
    __shared__ float si[64];
    __shared__ float sb[BB + 1];
    __shared__ double wacc[4];
    int tid = threadIdx.x;
    if (tid < 64) si[tid] = innerPad[tid];
    if (tid <= BB) sb[tid] = bounds[tid];
    __syncthreads();
    int g = (blockIdx.x * 256 + tid) * 4;          // 4 events per thread
    float4 tm4 = *(const float4*)(times + g);
    int4 pd4 = *(const int4*)(epid + g);
    float tms[4] = {tm4.x, tm4.y, tm4.z, tm4.w};
    int pids[4] = {pd4.x, pd4.y, pd4.z, pd4.w};
    int cc[4];
    float rem[4];
#pragma unroll
    for (int k = 0; k < 4; k++) {
        int c = 0;  // searchsorted(inner, tm, 'right') via binary search over padded 64
        float tm = tms[k];
#pragma unroll
        for (int s = 32; s >= 1; s >>= 1)
            if (si[c + s - 1] <= tm) c += s;
        cc[k] = c;
        rem[k] = tm - sb[c];
    }
    // 4 independent gathers in flight together
    float4 e0 = table[(size_t)pids[0] * BB + cc[0]];
    float4 e1 = table[(size_t)pids[1] * BB + cc[1]];
    float4 e2 = table[(size_t)pids[2] * BB + cc[2]];
    float4 e3 = table[(size_t)pids[3] * BB + cc[3]];
    float eacc = 0.f;
    {
        float d2 = fmaxf(fmaf(rem[0], fmaf(rem[0], e0.z, 2.f * e0.y), e0.x), 0.f);
        eacc += e0.w - __builtin_amdgcn_sqrtf(d2);
        d2 = fmaxf(fmaf(rem[1], fmaf(rem[1], e1.z, 2.f * e1.y), e1.x), 0.f);
        eacc += e1.w - __builtin_amdgcn_sqrtf(d2);
        d2 = fmaxf(fmaf(rem[2], fmaf(rem[2], e2.z, 2.f * e2.y), e2.x), 0.f);
        eacc += e2.w - __builtin_amdgcn_sqrtf(d2);
        d2 = fmaxf(fmaf(rem[3], fmaf(rem[3], e3.z, 2.f * e3.y), e3.x), 0.f);
        eacc += e3.w - __builtin_amdgcn_sqrtf(d2);
    }
    float val = reduce1(eacc);
    if ((tid & 63) == 0) wacc[tid >> 6] = (double)val;
    __syncthreads();
    if (tid == 0)
        atomicAdd(acc_out, -(wacc[0] + wacc[1] + wacc[2] + wacc[3]));
}

__global__ void k_finalize(const double* __restrict__ acc, float* __restrict__ out) {
    out[0] = (float)(*acc);
}

extern "C" void kernel_launch(void* const* d_in, const int* in_sizes, int n_in,
                              void* d_out, int out_size, void* d_ws, size_t ws_size,
                              hipStream_t stream) {
    const float* x0     = (const float*)d_in[0];
    const float* v      = (const float*)d_in[1];
    const float* beta   = (const float*)d_in[2];
    const float* brw    = (const float*)d_in[3];
    const float* etimes = (const float*)d_in[4];
    const int*   pairs  = (const int*)d_in[5];
    const int*   epid   = (const int*)d_in[6];

    char* ws = (char*)d_ws;
    double* acc     = (double*)ws;
    int* cnt        = (int*)(ws + 1024);
    int* cursor     = (int*)(ws + 9216);
    int* perm       = (int*)(ws + 17408);
    float* bounds   = (float*)(ws + 82944);
    float* widths   = (float*)(ws + 83456);
    float* innerPad = (float*)(ws + 83968);
    float4* table   = (float4*)(ws + 84480);

    (void)hipMemsetAsync(ws, 0, 9216, stream);  // acc + cnt

    hipLaunchKernelGGL(k_bounds, dim3(1), dim3(64), 0, stream, brw, bounds, widths, innerPad);
    hipLaunchKernelGGL(k_hist2, dim3(PP / 256), dim3(256), 0, stream, pairs, cnt);
    hipLaunchKernelGGL(k_scan2, dim3(1), dim3(1024), 0, stream, cnt, cursor);
    hipLaunchKernelGGL(k_scatter2, dim3(PP / 256), dim3(256), 0, stream, pairs, cursor, perm);
    hipLaunchKernelGGL(k_pairs, dim3(PP / 4), dim3(256), 0, stream, x0, v, beta, pairs,
                       perm, widths, table, acc);
    hipLaunchKernelGGL(k_events, dim3(TT / 1024), dim3(256), 0, stream, etimes, epid,
                       bounds, innerPad, table, acc);
    hipLaunchKernelGGL(k_finalize, dim3(1), dim3(1), 0, stream, acc, (float*)d_out);
}

// Round 9
// 94.119 us; speedup vs baseline: 1.2605x; 1.0569x over previous
//
#include <hip/hip_runtime.h>

#define NN 2048
#define DD 64
#define BB 64
#define PP 16384
#define TT 262144
#define EPSF 1e-6f
#define SS ((size_t)NN * DD)  // floats between consecutive bins of v (bin-major)

// ---------------- ws layout (bytes) ----------------
// 0     : double acc
// 1024  : int cnt[2048]     (node-i histogram)
// 9216  : int cursor[2048]
// 17408 : int perm[PP]      (pair ids sorted by node i)
// 82944 : float bounds[65]
// 83456 : float widths[64]
// 83968 : float innerPad[64]
// 84480 : float4 table[PP*BB]  (n2_left, d0, qq, bsum) = 16.78 MB

typedef unsigned uv2 __attribute__((ext_vector_type(2)));

template <int CTRL, int RM = 0xF, bool BC = true>
__device__ __forceinline__ float dpp_add(float x) {
    int y = __builtin_amdgcn_update_dpp(0, __float_as_int(x), CTRL, RM, 0xF, BC);
    return x + __int_as_float(y);
}

template <int PAT>
__device__ __forceinline__ float swz_add(float x) {
    return x + __int_as_float(__builtin_amdgcn_ds_swizzle(__float_as_int(x), PAT));
}

// xor16 / xor32 adds on the VALU pipe (permlane swaps), LDS fallback if absent
__device__ __forceinline__ float xor16_add(float x) {
#if __has_builtin(__builtin_amdgcn_permlane16_swap)
    uv2 r = __builtin_amdgcn_permlane16_swap(__float_as_uint(x), __float_as_uint(x),
                                             false, false);
    return __uint_as_float(r.x) + __uint_as_float(r.y);
#else
    return swz_add<0x401F>(x);
#endif
}
__device__ __forceinline__ float xor32_add(float x) {
#if __has_builtin(__builtin_amdgcn_permlane32_swap)
    uv2 r = __builtin_amdgcn_permlane32_swap(__float_as_uint(x), __float_as_uint(x),
                                             false, false);
    return __uint_as_float(r.x) + __uint_as_float(r.y);
#else
    return x + __shfl_xor(x, 32, 64);
#endif
}

// full 64-lane sum, result on all lanes
__device__ __forceinline__ float reduce1(float a) {
    a = dpp_add<0xB1>(a);     // quad_perm xor1
    a = dpp_add<0x4E>(a);     // quad_perm xor2
    a = dpp_add<0x141>(a);    // row_half_mirror (completes sum of 8)
    a = swz_add<0x201F>(a);   // xor8
    a = xor16_add(a);
    a = xor32_add(a);
    return a;
}

// 64-lane inclusive prefix sum (canonical 6-DPP scan)
__device__ __forceinline__ float incl_scan(float x) {
    x = dpp_add<0x111>(x);             // row_shr:1
    x = dpp_add<0x112>(x);             // row_shr:2
    x = dpp_add<0x114>(x);             // row_shr:4
    x = dpp_add<0x118>(x);             // row_shr:8
    x = dpp_add<0x142, 0xA, false>(x); // row_bcast:15 -> rows 1,3
    x = dpp_add<0x143, 0xC, false>(x); // row_bcast:31 -> rows 2,3
    return x;
}

__global__ void k_bounds(const float* __restrict__ brw, float* __restrict__ bounds,
                         float* __restrict__ widths, float* __restrict__ innerPad,
                         int* __restrict__ cnt, double* __restrict__ acc) {
    if (blockIdx.x != 0) {
        // blocks 1..8: zero cnt[2048] and acc (absorbs the old memset dispatch)
        int t = (blockIdx.x - 1) * 64 + threadIdx.x;  // 0..511
#pragma unroll
        for (int k = 0; k < 4; k++) cnt[t * 4 + k] = 0;
        if (blockIdx.x == 1 && threadIdx.x == 0) acc[0] = 0.0;
        return;
    }
    int lane = threadIdx.x;  // 64 threads
    float w = brw[lane];
    float m = w;
#pragma unroll
    for (int s = 32; s >= 1; s >>= 1) m = fmaxf(m, __shfl_xor(m, s, 64));
    float e = expf(w - m);
    float tot = e;
#pragma unroll
    for (int s = 32; s >= 1; s >>= 1) tot += __shfl_xor(tot, s, 64);
    float sm = e / tot;
    float c = sm;  // inclusive prefix sum
#pragma unroll
    for (int off = 1; off < 64; off <<= 1) {
        float t = __shfl_up(c, off, 64);
        if (lane >= off) c += t;
    }
    float cexcl = __shfl_up(c, 1, 64);
    if (lane == 0) cexcl = 0.f;
    if (lane == 0) bounds[0] = 0.f;
    bounds[lane + 1] = c;
    widths[lane] = c - cexcl;
    innerPad[lane] = (lane == 63) ? 3.4e38f : c;  // inner = bounds[1..63]
}

__global__ void k_hist2(const int* __restrict__ pairs, int* __restrict__ cnt) {
    int t = blockIdx.x * 256 + threadIdx.x;  // t < PP; pairs[t] = node i
    atomicAdd(&cnt[pairs[t]], 1);
}

__global__ __launch_bounds__(1024) void k_scan2(const int* __restrict__ cnt,
                                                int* __restrict__ cursor) {
    __shared__ int waveTot[16];
    __shared__ int waveOff[16];
    int tid = threadIdx.x;  // 1024 threads, 2 entries each
    int a = cnt[tid * 2], b = cnt[tid * 2 + 1];
    int s = a + b;
    int lane = tid & 63, wid = tid >> 6;
    int incl = s;
#pragma unroll
    for (int off = 1; off < 64; off <<= 1) {
        int t2 = __shfl_up(incl, off, 64);
        if (lane >= off) incl += t2;
    }
    if (lane == 63) waveTot[wid] = incl;
    __syncthreads();
    if (tid == 0) {
        int r = 0;
        for (int w = 0; w < 16; w++) { waveOff[w] = r; r += waveTot[w]; }
    }
    __syncthreads();
    int run = waveOff[wid] + (incl - s);  // exclusive prefix for this thread
    cursor[tid * 2] = run;
    cursor[tid * 2 + 1] = run + a;
}

__global__ void k_scatter2(const int* __restrict__ pairs, int* __restrict__ cursor,
                           int* __restrict__ perm) {
    int t = blockIdx.x * 256 + threadIdx.x;
    int pos = atomicAdd(&cursor[pairs[t]], 1);
    perm[pos] = t;
}

__global__ __launch_bounds__(256) void k_pairs(
    const float* __restrict__ x0, const float* __restrict__ v,
    const float* __restrict__ beta, const int* __restrict__ pairs,
    const int* __restrict__ perm, const float* __restrict__ widths,
    float4* __restrict__ table, double* __restrict__ acc_out) {
    __shared__ double bacc[4];
    const int wid = threadIdx.x >> 6;
    const int lane = threadIdx.x & 63;
    const int bid = blockIdx.x;
    const int vb = ((bid & 7) << 9) | (bid >> 3);  // XCD-contiguous p-ranges (4096 blocks)
    const int p = perm[vb * 4 + wid];

    const int i = pairs[p];
    const int j = pairs[PP + p];
    const float bsum = beta[i] + beta[j];

    float dx0 = x0[i * DD + lane] - x0[j * DD + lane];
    float xt = dx0;
    float n2_0 = reduce1(dx0 * dx0);
    float rr0 = __builtin_amdgcn_sqrtf(n2_0);
    float numer0 = rr0 * __expf(bsum - rr0);

    const float* __restrict__ pi = v + (size_t)i * DD + lane;
    const float* __restrict__ pj = v + (size_t)j * DD + lane;

    const int cls = lane & 7;   // class-select id
    const int grp = lane >> 3;  // chunk-gate id

    float d0r = 0.f, qqr = 0.f;  // lane b ends holding bin b's reduced d0, qq
    float b0A[8], b0B[8], b1A[8], b1B[8], b2A[8], b2B[8];
#pragma unroll
    for (int b = 0; b < 8; b++) {  // chunk 0
        b0A[b] = pi[(size_t)b * SS];
        b0B[b] = pj[(size_t)b * SS];
    }
#pragma unroll
    for (int b = 0; b < 8; b++) {  // chunk 1
        b1A[b] = pi[(size_t)(8 + b) * SS];
        b1B[b] = pj[(size_t)(8 + b) * SS];
    }

#pragma unroll
    for (int c = 0; c < 8; c++) {
        if (c < 6) {  // 2-chunk-deep prefetch (~2 chunks of compute to cover latency)
#pragma unroll
            for (int b = 0; b < 8; b++) {
                b2A[b] = pi[(size_t)((c + 2) * 8 + b) * SS];
                b2B[b] = pj[(size_t)((c + 2) * 8 + b) * SS];
            }
        }
        float zd = 0.f, zq = 0.f;  // lane l: class-(l>>3) partial of bin (8c + (l&7))
#pragma unroll
        for (int b = 0; b < 8; b++) {
            float dv = b0A[b] - b0B[b];
            float d0p = xt * dv;
            float qqp = dv * dv;
            // 3 DPP levels: every lane of each 8-lane group holds that group's sum
            d0p = dpp_add<0xB1>(d0p);  qqp = dpp_add<0xB1>(qqp);   // xor1
            d0p = dpp_add<0x4E>(d0p);  qqp = dpp_add<0x4E>(qqp);   // xor2
            d0p = dpp_add<0x141>(d0p); qqp = dpp_add<0x141>(qqp);  // half-mirror
            if (cls == b) { zd = d0p; zq = qqp; }  // stash bin b's partials
            // widths[const] is wave-uniform -> scalar load, off the VALU chain
            xt = fmaf(dv, widths[c * 8 + b], xt);
        }
        // cross-class reduce for all 8 bins at once: sum lanes {b, b+8, ..., b+56}
        zd = swz_add<0x201F>(zd);  zq = swz_add<0x201F>(zq);  // xor8
        zd = xor16_add(zd);        zq = xor16_add(zq);
        zd = xor32_add(zd);        zq = xor32_add(zq);
        // lane l now holds the full sum of bin 8c+(l&7); keep where lane==bin
        if (grp == c) { d0r = zd; qqr = zq; }
        // rotate pipeline buffers (full unroll -> pure register renaming)
#pragma unroll
        for (int b = 0; b < 8; b++) {
            b0A[b] = b1A[b]; b0B[b] = b1B[b];
            b1A[b] = b2A[b]; b1B[b] = b2B[b];
        }
    }

    // phase 3: all 64 bins' scalar math lane-parallel (lane = bin)
    float wl = widths[lane];
    float tt = wl * fmaf(wl, qqr, 2.f * d0r);     // n2 increment of bin `lane`
    float incl = incl_scan(tt);
    float n2L = fmaxf(n2_0 + (incl - tt), 0.f);   // left-boundary norm^2
    float n2R = fmaxf(n2_0 + incl, 0.f);          // right-boundary norm^2
    float rrR = __builtin_amdgcn_sqrtf(n2R);
    float numerR = rrR * __expf(bsum - rrR);
    // numerL = numerR of lane-1 via DPP wave_shr:1 (lane 0 patched below)
    float numerL = __int_as_float(
        __builtin_amdgcn_update_dpp(0, __float_as_int(numerR), 0x138, 0xF, 0xF, true));
    numerL = (lane == 0) ? numer0 : numerL;
    float pd = fmaf(wl, qqr, d0r);                // dot1 = d0 + w*qq
    float term = numerR * __builtin_amdgcn_rcpf(pd + EPSF)
               - numerL * __builtin_amdgcn_rcpf(d0r + EPSF);
    float acc = reduce1(term);

    table[(size_t)p * BB + lane] = make_float4(n2L, d0r, qqr, bsum);

    if (lane == 0) bacc[wid] = (double)acc;
    __syncthreads();
    if (threadIdx.x == 0)
        atomicAdd(acc_out, bacc[0] + bacc[1] + bacc[2] + bacc[3]);
}

__global__ __launch_bounds__(256) void k_events(
    const float* __restrict__ times, const int* __restrict__ epid,
    const float* __restrict__ bounds, const float* __restrict__ innerPad,
    const float4* __restrict__ table, double* __restrict__ acc_out) {
    __shared__ float si[64];
    __shared__ float sb[BB + 1];
    __shared__ double wacc[4];
    int tid = threadIdx.x;
    if (tid < 64) si[tid] = innerPad[tid];
    if (tid <= BB) sb[tid] = bounds[tid];
    __syncthreads();
    int g = (blockIdx.x * 256 + tid) * 4;          // 4 events per thread
    float4 tm4 = *(const float4*)(times + g);
    int4 pd4 = *(const int4*)(epid + g);
    float tms[4] = {tm4.x, tm4.y, tm4.z, tm4.w};
    int pids[4] = {pd4.x, pd4.y, pd4.z, pd4.w};
    int cc[4];
    float rem[4];
#pragma unroll
    for (int k = 0; k < 4; k++) {
        int c = 0;  // searchsorted(inner, tm, 'right') via binary search over padded 64
        float tm = tms[k];
#pragma unroll
        for (int s = 32; s >= 1; s >>= 1)
            if (si[c + s - 1] <= tm) c += s;
        cc[k] = c;
        rem[k] = tm - sb[c];
    }
    // 4 independent gathers in flight together
    float4 e0 = table[(size_t)pids[0] * BB + cc[0]];
    float4 e1 = table[(size_t)pids[1] * BB + cc[1]];
    float4 e2 = table[(size_t)pids[2] * BB + cc[2]];
    float4 e3 = table[(size_t)pids[3] * BB + cc[3]];
    float eacc = 0.f;
    {
        float d2 = fmaxf(fmaf(rem[0], fmaf(rem[0], e0.z, 2.f * e0.y), e0.x), 0.f);
        eacc += e0.w - __builtin_amdgcn_sqrtf(d2);
        d2 = fmaxf(fmaf(rem[1], fmaf(rem[1], e1.z, 2.f * e1.y), e1.x), 0.f);
        eacc += e1.w - __builtin_amdgcn_sqrtf(d2);
        d2 = fmaxf(fmaf(rem[2], fmaf(rem[2], e2.z, 2.f * e2.y), e2.x), 0.f);
        eacc += e2.w - __builtin_amdgcn_sqrtf(d2);
        d2 = fmaxf(fmaf(rem[3], fmaf(rem[3], e3.z, 2.f * e3.y), e3.x), 0.f);
        eacc += e3.w - __builtin_amdgcn_sqrtf(d2);
    }
    float val = reduce1(eacc);
    if ((tid & 63) == 0) wacc[tid >> 6] = (double)val;
    __syncthreads();
    if (tid == 0)
        atomicAdd(acc_out, -(wacc[0] + wacc[1] + wacc[2] + wacc[3]));
}

__global__ void k_finalize(const double* __restrict__ acc, float* __restrict__ out) {
    out[0] = (float)(*acc);
}

extern "C" void kernel_launch(void* const* d_in, const int* in_sizes, int n_in,
                              void* d_out, int out_size, void* d_ws, size_t ws_size,
                              hipStream_t stream) {
    const float* x0     = (const float*)d_in[0];
    const float* v      = (const float*)d_in[1];
    const float* beta   = (const float*)d_in[2];
    const float* brw    = (const float*)d_in[3];
    const float* etimes = (const float*)d_in[4];
    const int*   pairs  = (const int*)d_in[5];
    const int*   epid   = (const int*)d_in[6];

    char* ws = (char*)d_ws;
    double* acc     = (double*)ws;
    int* cnt        = (int*)(ws + 1024);
    int* cursor     = (int*)(ws + 9216);
    int* perm       = (int*)(ws + 17408);
    float* bounds   = (float*)(ws + 82944);
    float* widths   = (float*)(ws + 83456);
    float* innerPad = (float*)(ws + 83968);
    float4* table   = (float4*)(ws + 84480);

    hipLaunchKernelGGL(k_bounds, dim3(9), dim3(64), 0, stream, brw, bounds, widths,
                       innerPad, cnt, acc);
    hipLaunchKernelGGL(k_hist2, dim3(PP / 256), dim3(256), 0, stream, pairs, cnt);
    hipLaunchKernelGGL(k_scan2, dim3(1), dim3(1024), 0, stream, cnt, cursor);
    hipLaunchKernelGGL(k_scatter2, dim3(PP / 256), dim3(256), 0, stream, pairs, cursor, perm);
    hipLaunchKernelGGL(k_pairs, dim3(PP / 4), dim3(256), 0, stream, x0, v, beta, pairs,
                       perm, widths, table, acc);
    hipLaunchKernelGGL(k_events, dim3(TT / 1024), dim3(256), 0, stream, etimes, epid,
                       bounds, innerPad, table, acc);
    hipLaunchKernelGGL(k_finalize, dim3(1), dim3(1), 0, stream, acc, (float*)d_out);
}